// Round 4
// baseline (5489.754 us; speedup 1.0000x reference)
//
#include <hip/hip_runtime.h>
#include <hip/hip_bf16.h>

#define HID 128
#define N_NODES 50000
#define N_HEDGES 10000

// ---------------- histogram (degrees) ----------------
__global__ void hist_kernel(const int* __restrict__ node_idx,
                            const int* __restrict__ hedge_idx,
                            int* __restrict__ cnt_n, int* __restrict__ cnt_e, int nnz) {
    int i = blockIdx.x * blockDim.x + threadIdx.x;
    if (i < nnz) {
        atomicAdd(&cnt_n[node_idx[i]], 1);
        atomicAdd(&cnt_e[hedge_idx[i]], 1);
    }
}

// ---------------- exclusive scan (2 blocks: 0->hyperedges, 1->nodes) ----------------
__global__ __launch_bounds__(1024) void scan2_kernel(
        const int* __restrict__ cnt_e, int* __restrict__ off_e, int* __restrict__ cur_e,
        const int* __restrict__ cnt_n, int* __restrict__ off_n, int* __restrict__ cur_n) {
    const int* cnt; int* off; int* cur; int n;
    if (blockIdx.x == 0) { cnt = cnt_e; off = off_e; cur = cur_e; n = N_HEDGES; }
    else                 { cnt = cnt_n; off = off_n; cur = cur_n; n = N_NODES; }

    __shared__ int wsum[16];
    __shared__ int carry;
    int t = threadIdx.x, lane = t & 63, w = t >> 6;
    if (t == 0) carry = 0;
    __syncthreads();

    for (int base = 0; base < n; base += 1024) {
        int i = base + t;
        int v = (i < n) ? cnt[i] : 0;
        int incl = v;
        #pragma unroll
        for (int d = 1; d < 64; d <<= 1) {
            int tmp = __shfl_up(incl, d);
            if (lane >= d) incl += tmp;
        }
        if (lane == 63) wsum[w] = incl;
        __syncthreads();
        if (t == 0) {
            int run = carry;
            #pragma unroll
            for (int k = 0; k < 16; ++k) { int s = wsum[k]; wsum[k] = run; run += s; }
            carry = run;
        }
        __syncthreads();
        int excl = wsum[w] + incl - v;
        if (i < n) { off[i] = excl; cur[i] = excl; }
        __syncthreads();
    }
    if (t == 0) off[n] = carry;
}

// ---------------- CSR fill ----------------
__global__ void fill_kernel(const int* __restrict__ node_idx,
                            const int* __restrict__ hedge_idx,
                            int* __restrict__ cur_e, int* __restrict__ cur_n,
                            int* __restrict__ col_e, int* __restrict__ col_n, int nnz) {
    int i = blockIdx.x * blockDim.x + threadIdx.x;
    if (i < nnz) {
        int nd = node_idx[i], he = hedge_idx[i];
        col_e[atomicAdd(&cur_e[he], 1)] = nd;   // hyperedge -> member nodes
        col_n[atomicAdd(&cur_n[nd], 1)] = he;   // node -> incident hyperedges
    }
}

// ---------------- gather-aggregate: dst[b] = mean of src rows in segment b ----------------
__global__ void agg_kernel(const float* __restrict__ src, const int* __restrict__ col,
                           const int* __restrict__ off, float* __restrict__ dst) {
    int b = blockIdx.x;
    int c = threadIdx.x;                 // 128 threads = one HID column each
    int s = off[b], e = off[b + 1];
    float a0 = 0.f, a1 = 0.f, a2 = 0.f, a3 = 0.f;
    int j = s;
    for (; j + 3 < e; j += 4) {
        int i0 = col[j], i1 = col[j + 1], i2 = col[j + 2], i3 = col[j + 3];
        a0 += src[i0 * HID + c];
        a1 += src[i1 * HID + c];
        a2 += src[i2 * HID + c];
        a3 += src[i3 * HID + c];
    }
    for (; j < e; ++j) a0 += src[col[j] * HID + c];
    int cnt = e - s;
    float inv = (cnt > 0) ? 1.0f / (float)cnt : 0.0f;
    dst[b * HID + c] = ((a0 + a1) + (a2 + a3)) * inv;
}

// ---------------- shared GEMM helpers ----------------
#define BR 32

__device__ __forceinline__ void stage_w_swizzled(const float* __restrict__ W, float* wl, int t) {
    // wl[c*128 + ((k4 ^ ((c>>2)&31))<<2) + kj]
    #pragma unroll
    for (int i = 0; i < 16; ++i) {
        int g = t * 4 + i * 1024;
        float4 wv = *(const float4*)(W + g);
        int c = g >> 7;
        int k4 = (g & 127) >> 2;
        *(float4*)(wl + c * HID + ((k4 ^ ((c >> 2) & 31)) << 2)) = wv;
    }
}

__device__ __forceinline__ void gemm_acc(const float* wl, const float* const inr[4],
                                         int tc, int c0, float4 acc[4]) {
    #pragma unroll
    for (int k4 = 0; k4 < 32; ++k4) {
        int swz = (k4 ^ tc) << 2;
        float4 w0 = *(const float4*)(wl + (c0 + 0) * HID + swz);
        float4 w1 = *(const float4*)(wl + (c0 + 1) * HID + swz);
        float4 w2 = *(const float4*)(wl + (c0 + 2) * HID + swz);
        float4 w3 = *(const float4*)(wl + (c0 + 3) * HID + swz);
        #pragma unroll
        for (int i = 0; i < 4; ++i) {
            float4 uv = *(const float4*)(inr[i] + (k4 << 2));
            acc[i].x += uv.x * w0.x + uv.y * w0.y + uv.z * w0.z + uv.w * w0.w;
            acc[i].y += uv.x * w1.x + uv.y * w1.y + uv.z * w1.z + uv.w * w1.w;
            acc[i].z += uv.x * w2.x + uv.y * w2.y + uv.z * w2.z + uv.w * w2.w;
            acc[i].w += uv.x * w3.x + uv.y * w3.y + uv.z * w3.z + uv.w * w3.w;
        }
    }
}

// ---------------- relu GEMM: out = relu(in @ W^T + b), in-place safe ----------------
__global__ __launch_bounds__(256) void gemm_relu_kernel(
        const float* in, const float* __restrict__ W,
        const float* __restrict__ bias, float* out, int M) {
    __shared__ float wl[HID * HID];      // 64 KB, XOR-swizzled
    int t = threadIdx.x;
    stage_w_swizzled(W, wl, t);
    __syncthreads();

    int tc = t & 31, tr = t >> 5;
    int r0 = blockIdx.x * BR + tr * 4;
    int c0 = tc * 4;

    const float* inr[4];
    #pragma unroll
    for (int i = 0; i < 4; ++i) {
        int r = r0 + i; if (r > M - 1) r = M - 1;
        inr[i] = in + (size_t)r * HID;
    }

    float4 acc[4];
    #pragma unroll
    for (int i = 0; i < 4; ++i) acc[i] = make_float4(0.f, 0.f, 0.f, 0.f);
    gemm_acc(wl, inr, tc, c0, acc);

    __syncthreads();   // in-place: all reads of this block's rows must finish

    float4 bv = *(const float4*)(bias + c0);
    #pragma unroll
    for (int i = 0; i < 4; ++i) {
        int r = r0 + i;
        if (r >= M) continue;
        float4 v = acc[i];
        v.x = fmaxf(v.x + bv.x, 0.f); v.y = fmaxf(v.y + bv.y, 0.f);
        v.z = fmaxf(v.z + bv.z, 0.f); v.w = fmaxf(v.w + bv.w, 0.f);
        *(float4*)(out + (size_t)r * HID + c0) = v;
    }
}

// ---------------- fused mean+logstd GEMM + reparameterization ----------------
// z = noise * exp(h @ Ws^T + bs) + (h @ Wm^T + bm), in-place (h and z alias)
__global__ __launch_bounds__(256) void gemm_vae_kernel(
        const float* h, const float* __restrict__ Wm, const float* __restrict__ bm,
        const float* __restrict__ Ws, const float* __restrict__ bs,
        const float* __restrict__ noise, float* z, int M) {
    __shared__ float wl[HID * HID];      // 64 KB, reused for Wm then Ws
    int t = threadIdx.x;
    int tc = t & 31, tr = t >> 5;
    int r0 = blockIdx.x * BR + tr * 4;
    int c0 = tc * 4;

    const float* inr[4];
    #pragma unroll
    for (int i = 0; i < 4; ++i) {
        int r = r0 + i; if (r > M - 1) r = M - 1;
        inr[i] = h + (size_t)r * HID;
    }

    // pass 1: mean accumulator
    stage_w_swizzled(Wm, wl, t);
    __syncthreads();
    float4 accM[4];
    #pragma unroll
    for (int i = 0; i < 4; ++i) accM[i] = make_float4(0.f, 0.f, 0.f, 0.f);
    gemm_acc(wl, inr, tc, c0, accM);
    __syncthreads();                     // everyone done reading Wm

    // pass 2: logstd accumulator (same LDS buffer)
    stage_w_swizzled(Ws, wl, t);
    __syncthreads();
    float4 accS[4];
    #pragma unroll
    for (int i = 0; i < 4; ++i) accS[i] = make_float4(0.f, 0.f, 0.f, 0.f);
    gemm_acc(wl, inr, tc, c0, accS);

    __syncthreads();                     // in-place: all reads of h rows done

    float4 bmv = *(const float4*)(bm + c0);
    float4 bsv = *(const float4*)(bs + c0);
    #pragma unroll
    for (int i = 0; i < 4; ++i) {
        int r = r0 + i;
        if (r >= M) continue;
        size_t o = (size_t)r * HID + c0;
        float4 nz = *(const float4*)(noise + o);
        float4 m = accM[i], s = accS[i], zv;
        zv.x = nz.x * expf(s.x + bsv.x) + m.x + bmv.x;
        zv.y = nz.y * expf(s.y + bsv.y) + m.y + bmv.y;
        zv.z = nz.z * expf(s.z + bsv.z) + m.z + bmv.z;
        zv.w = nz.w * expf(s.w + bsv.w) + m.w + bmv.w;
        *(float4*)(z + o) = zv;
    }
}

extern "C" void kernel_launch(void* const* d_in, const int* in_sizes, int n_in,
                              void* d_out, int out_size, void* d_ws, size_t ws_size,
                              hipStream_t stream) {
    const float* x      = (const float*)d_in[0];
    const int* node_idx = (const int*)d_in[1];
    const int* hedge_idx= (const int*)d_in[2];
    const float* noise  = (const float*)d_in[3];
    const float* Wc     = (const float*)d_in[4];
    const float* bc     = (const float*)d_in[5];
    const float* Wm     = (const float*)d_in[6];
    const float* bm     = (const float*)d_in[7];
    const float* Ws     = (const float*)d_in[8];
    const float* bs     = (const float*)d_in[9];
    float* out = (float*)d_out;          // doubles as u / h / z buffer
    const int nnz = in_sizes[1];

    // workspace carve-up (256B aligned), total ~18.6 MB
    char* p = (char*)d_ws;
    auto alloc = [&](size_t bytes) -> void* {
        void* r = (void*)p;
        p += (bytes + 255) & ~(size_t)255;
        return r;
    };
    int* cnt_e = (int*)alloc(N_HEDGES * 4);
    int* cnt_n = (int*)alloc(N_NODES * 4);
    int* off_e = (int*)alloc((N_HEDGES + 1) * 4);
    int* off_n = (int*)alloc((N_NODES + 1) * 4);
    int* cur_e = (int*)alloc(N_HEDGES * 4);
    int* cur_n = (int*)alloc(N_NODES * 4);
    int* col_e = (int*)alloc((size_t)nnz * 4);
    int* col_n = (int*)alloc((size_t)nnz * 4);
    float* e0  = (float*)alloc((size_t)N_HEDGES * HID * 4);

    hipMemsetAsync(cnt_e, 0, N_HEDGES * 4, stream);
    hipMemsetAsync(cnt_n, 0, N_NODES * 4, stream);

    int nb = (nnz + 255) / 256;
    hist_kernel<<<nb, 256, 0, stream>>>(node_idx, hedge_idx, cnt_n, cnt_e, nnz);
    scan2_kernel<<<2, 1024, 0, stream>>>(cnt_e, off_e, cur_e, cnt_n, off_n, cur_n);
    fill_kernel<<<nb, 256, 0, stream>>>(node_idx, hedge_idx, cur_e, cur_n, col_e, col_n, nnz);

    // e0 = B^-1 * H^T x   (aggregate x rows per hyperedge)
    agg_kernel<<<N_HEDGES, HID, 0, stream>>>(x, col_e, off_e, e0);
    // u = D^-1 * H e0     (aggregate e0 rows per node) -> d_out
    agg_kernel<<<N_NODES, HID, 0, stream>>>(e0, col_n, off_n, out);

    int gg = (N_NODES + BR - 1) / BR;
    // h = relu(u @ Wc^T + bc), in-place in d_out
    gemm_relu_kernel<<<gg, 256, 0, stream>>>(out, Wc, bc, out, N_NODES);
    // z = noise*exp(h @ Ws^T + bs) + (h @ Wm^T + bm), in-place in d_out
    gemm_vae_kernel<<<gg, 256, 0, stream>>>(out, Wm, bm, Ws, bs, noise, out, N_NODES);
}

// Round 7
// 795.784 us; speedup vs baseline: 6.8986x; 6.8986x over previous
//
#include <hip/hip_runtime.h>
#include <hip/hip_bf16.h>

#define HID 128
#define N_NODES 50000
#define N_HEDGES 10000

// ---------------- histogram (degrees) ----------------
__global__ void hist_kernel(const int* __restrict__ node_idx,
                            const int* __restrict__ hedge_idx,
                            int* __restrict__ cnt_n, int* __restrict__ cnt_e, int nnz) {
    int i = blockIdx.x * blockDim.x + threadIdx.x;
    if (i < nnz) {
        atomicAdd(&cnt_n[node_idx[i]], 1);
        atomicAdd(&cnt_e[hedge_idx[i]], 1);
    }
}

// ---------------- exclusive scan (2 blocks: 0->hyperedges, 1->nodes) ----------------
__global__ __launch_bounds__(1024) void scan2_kernel(
        const int* __restrict__ cnt_e, int* __restrict__ off_e, int* __restrict__ cur_e,
        const int* __restrict__ cnt_n, int* __restrict__ off_n, int* __restrict__ cur_n) {
    const int* cnt; int* off; int* cur; int n;
    if (blockIdx.x == 0) { cnt = cnt_e; off = off_e; cur = cur_e; n = N_HEDGES; }
    else                 { cnt = cnt_n; off = off_n; cur = cur_n; n = N_NODES; }

    __shared__ int wsum[16];
    __shared__ int carry;
    int t = threadIdx.x, lane = t & 63, w = t >> 6;
    if (t == 0) carry = 0;
    __syncthreads();

    for (int base = 0; base < n; base += 1024) {
        int i = base + t;
        int v = (i < n) ? cnt[i] : 0;
        int incl = v;
        #pragma unroll
        for (int d = 1; d < 64; d <<= 1) {
            int tmp = __shfl_up(incl, d);
            if (lane >= d) incl += tmp;
        }
        if (lane == 63) wsum[w] = incl;
        __syncthreads();
        if (t == 0) {
            int run = carry;
            #pragma unroll
            for (int k = 0; k < 16; ++k) { int s = wsum[k]; wsum[k] = run; run += s; }
            carry = run;
        }
        __syncthreads();
        int excl = wsum[w] + incl - v;
        if (i < n) { off[i] = excl; cur[i] = excl; }
        __syncthreads();
    }
    if (t == 0) off[n] = carry;
}

// ---------------- CSR fill ----------------
__global__ void fill_kernel(const int* __restrict__ node_idx,
                            const int* __restrict__ hedge_idx,
                            int* __restrict__ cur_e, int* __restrict__ cur_n,
                            int* __restrict__ col_e, int* __restrict__ col_n, int nnz) {
    int i = blockIdx.x * blockDim.x + threadIdx.x;
    if (i < nnz) {
        int nd = node_idx[i], he = hedge_idx[i];
        col_e[atomicAdd(&cur_e[he], 1)] = nd;   // hyperedge -> member nodes
        col_n[atomicAdd(&cur_n[nd], 1)] = he;   // node -> incident hyperedges
    }
}

// ---------------- gather-aggregate: dst[b] = mean of src rows in segment b ----------------
__global__ void agg_kernel(const float* __restrict__ src, const int* __restrict__ col,
                           const int* __restrict__ off, float* __restrict__ dst) {
    int b = blockIdx.x;
    int c = threadIdx.x;                 // 128 threads = one HID column each
    int s = off[b], e = off[b + 1];
    float a0 = 0.f, a1 = 0.f, a2 = 0.f, a3 = 0.f;
    int j = s;
    for (; j + 3 < e; j += 4) {
        int i0 = col[j], i1 = col[j + 1], i2 = col[j + 2], i3 = col[j + 3];
        a0 += src[i0 * HID + c];
        a1 += src[i1 * HID + c];
        a2 += src[i2 * HID + c];
        a3 += src[i3 * HID + c];
    }
    for (; j < e; ++j) a0 += src[col[j] * HID + c];
    int cnt = e - s;
    float inv = (cnt > 0) ? 1.0f / (float)cnt : 0.0f;
    dst[b * HID + c] = ((a0 + a1) + (a2 + a3)) * inv;
}

// ---------------- shared GEMM helpers ----------------
#define BR 32

__device__ __forceinline__ void stage_w_swizzled(const float* __restrict__ W, float* wl, int t) {
    // wl[c*128 + ((k4 ^ ((c>>2)&31))<<2) + kj]
    #pragma unroll
    for (int i = 0; i < 16; ++i) {
        int g = t * 4 + i * 1024;
        float4 wv = *(const float4*)(W + g);
        int c = g >> 7;
        int k4 = (g & 127) >> 2;
        *(float4*)(wl + c * HID + ((k4 ^ ((c >> 2) & 31)) << 2)) = wv;
    }
}

// NOTE: unroll capped at 4. Full unroll let the compiler hoist ~128 float4
// loads, blew past 256 VGPRs, and spilled accumulators to scratch inside the
// hot loop (rocprof r4: VGPR=256, 4GB FETCH + 3GB WRITE per dispatch, VALUBusy 1.5%).
__device__ __forceinline__ void gemm_acc(const float* wl, const float* const inr[4],
                                         int tc, int c0, float4 acc[4]) {
    #pragma unroll 4
    for (int k4 = 0; k4 < 32; ++k4) {
        int swz = (k4 ^ tc) << 2;
        float4 w0 = *(const float4*)(wl + (c0 + 0) * HID + swz);
        float4 w1 = *(const float4*)(wl + (c0 + 1) * HID + swz);
        float4 w2 = *(const float4*)(wl + (c0 + 2) * HID + swz);
        float4 w3 = *(const float4*)(wl + (c0 + 3) * HID + swz);
        #pragma unroll
        for (int i = 0; i < 4; ++i) {
            float4 uv = *(const float4*)(inr[i] + (k4 << 2));
            acc[i].x += uv.x * w0.x + uv.y * w0.y + uv.z * w0.z + uv.w * w0.w;
            acc[i].y += uv.x * w1.x + uv.y * w1.y + uv.z * w1.z + uv.w * w1.w;
            acc[i].z += uv.x * w2.x + uv.y * w2.y + uv.z * w2.z + uv.w * w2.w;
            acc[i].w += uv.x * w3.x + uv.y * w3.y + uv.z * w3.z + uv.w * w3.w;
        }
    }
}

// ---------------- relu GEMM: out = relu(in @ W^T + b), in-place safe ----------------
__global__ __launch_bounds__(256) void gemm_relu_kernel(
        const float* in, const float* __restrict__ W,
        const float* __restrict__ bias, float* out, int M) {
    __shared__ float wl[HID * HID];      // 64 KB, XOR-swizzled
    int t = threadIdx.x;
    stage_w_swizzled(W, wl, t);
    __syncthreads();

    int tc = t & 31, tr = t >> 5;
    int r0 = blockIdx.x * BR + tr * 4;
    int c0 = tc * 4;

    const float* inr[4];
    #pragma unroll
    for (int i = 0; i < 4; ++i) {
        int r = r0 + i; if (r > M - 1) r = M - 1;
        inr[i] = in + (size_t)r * HID;
    }

    float4 acc[4];
    #pragma unroll
    for (int i = 0; i < 4; ++i) acc[i] = make_float4(0.f, 0.f, 0.f, 0.f);
    gemm_acc(wl, inr, tc, c0, acc);

    __syncthreads();   // in-place: all reads of this block's rows must finish

    float4 bv = *(const float4*)(bias + c0);
    #pragma unroll
    for (int i = 0; i < 4; ++i) {
        int r = r0 + i;
        if (r >= M) continue;
        float4 v = acc[i];
        v.x = fmaxf(v.x + bv.x, 0.f); v.y = fmaxf(v.y + bv.y, 0.f);
        v.z = fmaxf(v.z + bv.z, 0.f); v.w = fmaxf(v.w + bv.w, 0.f);
        *(float4*)(out + (size_t)r * HID + c0) = v;
    }
}

// ---------------- fused mean+logstd GEMM + reparameterization ----------------
// z = noise * exp(h @ Ws^T + bs) + (h @ Wm^T + bm), in-place (h and z alias)
__global__ __launch_bounds__(256) void gemm_vae_kernel(
        const float* h, const float* __restrict__ Wm, const float* __restrict__ bm,
        const float* __restrict__ Ws, const float* __restrict__ bs,
        const float* __restrict__ noise, float* z, int M) {
    __shared__ float wl[HID * HID];      // 64 KB, reused for Wm then Ws
    int t = threadIdx.x;
    int tc = t & 31, tr = t >> 5;
    int r0 = blockIdx.x * BR + tr * 4;
    int c0 = tc * 4;

    const float* inr[4];
    #pragma unroll
    for (int i = 0; i < 4; ++i) {
        int r = r0 + i; if (r > M - 1) r = M - 1;
        inr[i] = h + (size_t)r * HID;
    }

    // pass 1: mean accumulator
    stage_w_swizzled(Wm, wl, t);
    __syncthreads();
    float4 accM[4];
    #pragma unroll
    for (int i = 0; i < 4; ++i) accM[i] = make_float4(0.f, 0.f, 0.f, 0.f);
    gemm_acc(wl, inr, tc, c0, accM);
    __syncthreads();                     // everyone done reading Wm

    // pass 2: logstd accumulator (same LDS buffer)
    stage_w_swizzled(Ws, wl, t);
    __syncthreads();
    float4 accS[4];
    #pragma unroll
    for (int i = 0; i < 4; ++i) accS[i] = make_float4(0.f, 0.f, 0.f, 0.f);
    gemm_acc(wl, inr, tc, c0, accS);

    __syncthreads();                     // in-place: all reads of h rows done

    float4 bmv = *(const float4*)(bm + c0);
    float4 bsv = *(const float4*)(bs + c0);
    #pragma unroll
    for (int i = 0; i < 4; ++i) {
        int r = r0 + i;
        if (r >= M) continue;
        size_t o = (size_t)r * HID + c0;
        float4 nz = *(const float4*)(noise + o);
        float4 m = accM[i], s = accS[i], zv;
        zv.x = nz.x * expf(s.x + bsv.x) + m.x + bmv.x;
        zv.y = nz.y * expf(s.y + bsv.y) + m.y + bmv.y;
        zv.z = nz.z * expf(s.z + bsv.z) + m.z + bmv.z;
        zv.w = nz.w * expf(s.w + bsv.w) + m.w + bmv.w;
        *(float4*)(z + o) = zv;
    }
}

extern "C" void kernel_launch(void* const* d_in, const int* in_sizes, int n_in,
                              void* d_out, int out_size, void* d_ws, size_t ws_size,
                              hipStream_t stream) {
    const float* x      = (const float*)d_in[0];
    const int* node_idx = (const int*)d_in[1];
    const int* hedge_idx= (const int*)d_in[2];
    const float* noise  = (const float*)d_in[3];
    const float* Wc     = (const float*)d_in[4];
    const float* bc     = (const float*)d_in[5];
    const float* Wm     = (const float*)d_in[6];
    const float* bm     = (const float*)d_in[7];
    const float* Ws     = (const float*)d_in[8];
    const float* bs     = (const float*)d_in[9];
    float* out = (float*)d_out;          // doubles as u / h / z buffer
    const int nnz = in_sizes[1];

    // workspace carve-up (256B aligned), total ~18.6 MB
    char* p = (char*)d_ws;
    auto alloc = [&](size_t bytes) -> void* {
        void* r = (void*)p;
        p += (bytes + 255) & ~(size_t)255;
        return r;
    };
    int* cnt_e = (int*)alloc(N_HEDGES * 4);
    int* cnt_n = (int*)alloc(N_NODES * 4);
    int* off_e = (int*)alloc((N_HEDGES + 1) * 4);
    int* off_n = (int*)alloc((N_NODES + 1) * 4);
    int* cur_e = (int*)alloc(N_HEDGES * 4);
    int* cur_n = (int*)alloc(N_NODES * 4);
    int* col_e = (int*)alloc((size_t)nnz * 4);
    int* col_n = (int*)alloc((size_t)nnz * 4);
    float* e0  = (float*)alloc((size_t)N_HEDGES * HID * 4);

    hipMemsetAsync(cnt_e, 0, N_HEDGES * 4, stream);
    hipMemsetAsync(cnt_n, 0, N_NODES * 4, stream);

    int nb = (nnz + 255) / 256;
    hist_kernel<<<nb, 256, 0, stream>>>(node_idx, hedge_idx, cnt_n, cnt_e, nnz);
    scan2_kernel<<<2, 1024, 0, stream>>>(cnt_e, off_e, cur_e, cnt_n, off_n, cur_n);
    fill_kernel<<<nb, 256, 0, stream>>>(node_idx, hedge_idx, cur_e, cur_n, col_e, col_n, nnz);

    // e0 = B^-1 * H^T x   (aggregate x rows per hyperedge)
    agg_kernel<<<N_HEDGES, HID, 0, stream>>>(x, col_e, off_e, e0);
    // u = D^-1 * H e0     (aggregate e0 rows per node) -> d_out
    agg_kernel<<<N_NODES, HID, 0, stream>>>(e0, col_n, off_n, out);

    int gg = (N_NODES + BR - 1) / BR;
    // h = relu(u @ Wc^T + bc), in-place in d_out
    gemm_relu_kernel<<<gg, 256, 0, stream>>>(out, Wc, bc, out, N_NODES);
    // z = noise*exp(h @ Ws^T + bs) + (h @ Wm^T + bm), in-place in d_out
    gemm_vae_kernel<<<gg, 256, 0, stream>>>(out, Wm, bm, Ws, bs, noise, out, N_NODES);
}